// Round 7
// baseline (4373.911 us; speedup 1.0000x reference)
//
#include <hip/hip_runtime.h>

#define N 8192
#define DK 256
#define LOG2E 1.4426950408889634f
#define LN2   0.6931471805599453f
#define ZS    2.5f            // int8 dequant scale (Zl = q * ZS)
#define QS    1.1541560327f   // 2*log2e / ZS  (fp32 acc -> q units)
#define BIAS  320.0f          // 128 * ZS ; duals stored shifted by -BIAS
// log2(8192) = 13 exactly; (loga+logb) in log2 units = -26

typedef unsigned short u16;
typedef u16   ushort8 __attribute__((ext_vector_type(8)));
typedef __bf16 bf16x8 __attribute__((ext_vector_type(8)));
typedef float  f32x4  __attribute__((ext_vector_type(4)));

__device__ __forceinline__ u16 f2bf(float f){
  unsigned u = __builtin_bit_cast(unsigned, f);
  return (u16)((u + 0x7fffu + ((u >> 16) & 1u)) >> 16);   // RNE fp32->bf16
}
__device__ __forceinline__ float ex2(float x){            // v_exp_f32 = 2^x
  float r; asm("v_exp_f32 %0, %1" : "=v"(r) : "v"(x)); return r;
}
__device__ __forceinline__ float lg2(float x){            // v_log_f32 = log2(x)
  float r; asm("v_log_f32 %0, %1" : "=v"(r) : "v"(x)); return r;
}
__device__ __forceinline__ float cub0(unsigned u){ float r; asm("v_cvt_f32_ubyte0 %0, %1":"=v"(r):"v"(u)); return r; }
__device__ __forceinline__ float cub1(unsigned u){ float r; asm("v_cvt_f32_ubyte1 %0, %1":"=v"(r):"v"(u)); return r; }
__device__ __forceinline__ float cub2(unsigned u){ float r; asm("v_cvt_f32_ubyte2 %0, %1":"=v"(r):"v"(u)); return r; }
__device__ __forceinline__ float cub3(unsigned u){ float r; asm("v_cvt_f32_ubyte3 %0, %1":"=v"(r):"v"(u)); return r; }

// monotone float <-> uint key (for atomicMax on floats of any sign)
__device__ __forceinline__ unsigned fkey(float f){
  unsigned b = __float_as_uint(f);
  return (b & 0x80000000u) ? ~b : (b | 0x80000000u);
}
__device__ __forceinline__ float fdec(unsigned k){
  unsigned b = (k & 0x80000000u) ? (k ^ 0x80000000u) : ~k;
  return __uint_as_float(b);
}

// ---------------------------------------------------------------------------
// prep: row sum-of-squares + bf16 copies + init gts = -y2*LOG2E - BIAS (g0=0)
// ---------------------------------------------------------------------------
__global__ __launch_bounds__(256) void prep_k(const float* __restrict__ x, const float* __restrict__ y,
                                              u16* __restrict__ xb, u16* __restrict__ yb,
                                              float* __restrict__ x2, float* __restrict__ y2,
                                              float* __restrict__ gts){
  const int w = threadIdx.x >> 6, l = threadIdx.x & 63;
  const int r = blockIdx.x * 4 + w;         // 0..16383
  const bool isx = r < N;
  const int rr = isx ? r : r - N;
  const float* src = (isx ? x : y) + (size_t)rr * DK;
  float4 v = *(const float4*)(src + l * 4);
  ushort4 bv;
  bv.x = f2bf(v.x); bv.y = f2bf(v.y); bv.z = f2bf(v.z); bv.w = f2bf(v.w);
  *(ushort4*)((isx ? xb : yb) + (size_t)rr * DK + l * 4) = bv;
  float p = v.x*v.x + v.y*v.y + v.z*v.z + v.w*v.w;
  #pragma unroll
  for (int off = 32; off > 0; off >>= 1) p += __shfl_down(p, off);
  if (l == 0){
    if (isx) x2[rr] = p;
    else { y2[rr] = p; gts[rr] = -p * LOG2E - BIAS; }
  }
}

// ---------------------------------------------------------------------------
// zero_k: zero the gmax key buffers (must happen every call, before use)
// ---------------------------------------------------------------------------
__global__ __launch_bounds__(256) void zero_k(unsigned* __restrict__ g){
  g[blockIdx.x * 256 + threadIdx.x] = 0u;
}

// ---------------------------------------------------------------------------
// gemm: z = xb*yb^T (bf16 MFMA). Quantize Zl = 2*log2e*z to biased uint8,
// stage tiles in LDS, store zq and zqT coalesced dwordx4.
// ---------------------------------------------------------------------------
__global__ __launch_bounds__(256) void gemm_k(const u16* __restrict__ xb, const u16* __restrict__ yb,
                                              unsigned char* __restrict__ zq,
                                              unsigned char* __restrict__ zqT){
  __shared__ __align__(16) u16 As[128 * 72];
  __shared__ __align__(16) u16 Bs[128 * 72];
  const int t = threadIdx.x;
  const int w = t >> 6, l = t & 63;
  const int wm = w >> 1, wn = w & 1;
  const int brow = blockIdx.y * 128, bcol = blockIdx.x * 128;
  const int tr = t >> 3, tc = t & 7;
  f32x4 acc[4][4] = {};
  for (int ks = 0; ks < 4; ++ks){
    #pragma unroll
    for (int rr = 0; rr < 4; ++rr){
      const int row = tr + rr * 32;
      *(ushort8*)&As[row * 72 + tc * 8] = *(const ushort8*)&xb[(size_t)(brow + row) * DK + ks * 64 + tc * 8];
      *(ushort8*)&Bs[row * 72 + tc * 8] = *(const ushort8*)&yb[(size_t)(bcol + row) * DK + ks * 64 + tc * 8];
    }
    __syncthreads();
    #pragma unroll
    for (int kk = 0; kk < 2; ++kk){
      bf16x8 av[4], bv[4];
      #pragma unroll
      for (int mi = 0; mi < 4; ++mi){
        const int ar = wm * 64 + mi * 16 + (l & 15);
        av[mi] = __builtin_bit_cast(bf16x8, *(const ushort8*)&As[ar * 72 + kk * 32 + (l >> 4) * 8]);
      }
      #pragma unroll
      for (int ni = 0; ni < 4; ++ni){
        const int br = wn * 64 + ni * 16 + (l & 15);
        bv[ni] = __builtin_bit_cast(bf16x8, *(const ushort8*)&Bs[br * 72 + kk * 32 + (l >> 4) * 8]);
      }
      #pragma unroll
      for (int mi = 0; mi < 4; ++mi)
        #pragma unroll
        for (int ni = 0; ni < 4; ++ni)
          acc[mi][ni] = __builtin_amdgcn_mfma_f32_16x16x32_bf16(av[mi], bv[ni], acc[mi][ni], 0, 0, 0);
    }
    __syncthreads();
  }
  // quantize: Cs row-major [128][128]; Ct col-major [col][row] stride 144
  unsigned char* Cs = (unsigned char*)As;
  unsigned char* Ct = (unsigned char*)Bs;
  #pragma unroll
  for (int mi = 0; mi < 4; ++mi){
    const int rowb = wm * 64 + mi * 16 + (l >> 4) * 4;
    #pragma unroll
    for (int ni = 0; ni < 4; ++ni){
      const int col = wn * 64 + ni * 16 + (l & 15);
      unsigned pk = 0;
      #pragma unroll
      for (int rr = 0; rr < 4; ++rr){
        float q = fminf(fmaxf(acc[mi][ni][rr] * QS, -127.f), 127.f);
        unsigned b = (unsigned)((int)__builtin_rintf(q) + 128) & 255u;
        Cs[(rowb + rr) * 128 + col] = (unsigned char)b;
        pk |= b << (8 * rr);
      }
      *(unsigned*)(Ct + col * 144 + rowb) = pk;
    }
  }
  __syncthreads();
  const int trow0 = t >> 3, kseg = t & 7;
  #pragma unroll
  for (int ii = 0; ii < 4; ++ii){
    const int row = trow0 + ii * 32;
    int4 v = *(const int4*)(Cs + row * 128 + kseg * 16);
    *(int4*)(zq + (size_t)(brow + row) * N + bcol + kseg * 16) = v;
    int4 vt = *(const int4*)(Ct + row * 144 + kseg * 16);
    *(int4*)(zqT + (size_t)(bcol + row) * N + brow + kseg * 16) = vt;
  }
}

// ---------------------------------------------------------------------------
// sweept: bootstrap sweep with full online-max tracking (1 row/wave).
// Also stores pmax_out[i] = lse2 for the premax kernels.
// ---------------------------------------------------------------------------
__global__ __launch_bounds__(256) void sweept_k(const unsigned char* __restrict__ z,
                                                const float* __restrict__ din,
                                                float* __restrict__ dout,
                                                float* __restrict__ pmax_out){
  const int w = threadIdx.x >> 6, l = threadIdx.x & 63;
  const int i = blockIdx.x * 4 + w;
  const unsigned char* zr = z + (size_t)i * N + l * 16;
  float m = -1e30f, s = 0.f;
  uint4 zA = *(const uint4*)(zr);
  #pragma unroll
  for (int it = 0; it < 8; ++it){
    uint4 zB = zA;
    if (it < 7) zB = *(const uint4*)(zr + (it + 1) * 1024);
    const float* gp = din + it * 1024 + l * 16;
    const float4 g0 = *(const float4*)(gp);
    const float4 g1 = *(const float4*)(gp + 4);
    const float4 g2 = *(const float4*)(gp + 8);
    const float4 g3 = *(const float4*)(gp + 12);
    float tt[16];
    tt[0]  = __builtin_fmaf(cub0(zA.x), ZS, g0.x);
    tt[1]  = __builtin_fmaf(cub1(zA.x), ZS, g0.y);
    tt[2]  = __builtin_fmaf(cub2(zA.x), ZS, g0.z);
    tt[3]  = __builtin_fmaf(cub3(zA.x), ZS, g0.w);
    tt[4]  = __builtin_fmaf(cub0(zA.y), ZS, g1.x);
    tt[5]  = __builtin_fmaf(cub1(zA.y), ZS, g1.y);
    tt[6]  = __builtin_fmaf(cub2(zA.y), ZS, g1.z);
    tt[7]  = __builtin_fmaf(cub3(zA.y), ZS, g1.w);
    tt[8]  = __builtin_fmaf(cub0(zA.z), ZS, g2.x);
    tt[9]  = __builtin_fmaf(cub1(zA.z), ZS, g2.y);
    tt[10] = __builtin_fmaf(cub2(zA.z), ZS, g2.z);
    tt[11] = __builtin_fmaf(cub3(zA.z), ZS, g2.w);
    tt[12] = __builtin_fmaf(cub0(zA.w), ZS, g3.x);
    tt[13] = __builtin_fmaf(cub1(zA.w), ZS, g3.y);
    tt[14] = __builtin_fmaf(cub2(zA.w), ZS, g3.z);
    tt[15] = __builtin_fmaf(cub3(zA.w), ZS, g3.w);
    float a0 = fmaxf(tt[0], tt[1]),  a1 = fmaxf(tt[2], tt[3]);
    float a2 = fmaxf(tt[4], tt[5]),  a3 = fmaxf(tt[6], tt[7]);
    float a4 = fmaxf(tt[8], tt[9]),  a5 = fmaxf(tt[10], tt[11]);
    float a6 = fmaxf(tt[12], tt[13]), a7 = fmaxf(tt[14], tt[15]);
    float b0 = fmaxf(a0, a1), b1 = fmaxf(a2, a3), b2 = fmaxf(a4, a5), b3 = fmaxf(a6, a7);
    float nm = fmaxf(fmaxf(fmaxf(b0, b1), fmaxf(b2, b3)), m);
    float s0 = ex2(tt[0] - nm) + ex2(tt[1] - nm) + ex2(tt[2] - nm) + ex2(tt[3] - nm)
             + ex2(tt[4] - nm) + ex2(tt[5] - nm) + ex2(tt[6] - nm) + ex2(tt[7] - nm);
    float s1 = ex2(tt[8] - nm) + ex2(tt[9] - nm) + ex2(tt[10] - nm) + ex2(tt[11] - nm)
             + ex2(tt[12] - nm) + ex2(tt[13] - nm) + ex2(tt[14] - nm) + ex2(tt[15] - nm);
    s = __builtin_fmaf(s, ex2(m - nm), s0 + s1);
    m = nm;
    zA = zB;
  }
  #pragma unroll
  for (int off = 32; off > 0; off >>= 1){
    float om = __shfl_down(m, off);
    float os = __shfl_down(s, off);
    float nm = fmaxf(m, om);
    s = __builtin_fmaf(s, ex2(m - nm), os * ex2(om - nm));
    m = nm;
  }
  if (l == 0){
    float lse2 = m + lg2(s);          // true lse2 (bias cancels)
    dout[i] = 13.0f - lse2 - BIAS;
    pmax_out[i] = lse2;
  }
}

// ---------------------------------------------------------------------------
// rank_k: exact deterministic rank of 8192 floats (ties by index).
// src[rank] = original index.  Brute-force O(n^2): ~1 us, one-time.
// ---------------------------------------------------------------------------
__global__ __launch_bounds__(256) void rank_k(const float* __restrict__ key,
                                              int* __restrict__ src){
  const int j = blockIdx.x * 256 + threadIdx.x;   // grid 32
  const float v = key[j];
  int r = 0;
  for (int jj = 0; jj < N; jj += 4){
    const float4 k4 = *(const float4*)(key + jj);
    r += (k4.x < v) || (k4.x == v && (jj + 0) < j);
    r += (k4.y < v) || (k4.y == v && (jj + 1) < j);
    r += (k4.z < v) || (k4.z == v && (jj + 2) < j);
    r += (k4.w < v) || (k4.w == v && (jj + 3) < j);
  }
  src[r] = j;
}

// ---------------------------------------------------------------------------
// repackz: in-place column permutation of zq (cols by srcG) and zqT (cols by
// srcF), one block per physical row; also emits per-(row,64-chunk) max byte.
// Rows stay physical (sweeps indirect via srcRow).
// ---------------------------------------------------------------------------
__global__ __launch_bounds__(256) void repackz_k(unsigned char* __restrict__ zq,
                                                 unsigned char* __restrict__ zqT,
                                                 const int* __restrict__ srcG,
                                                 const int* __restrict__ srcF,
                                                 unsigned char* __restrict__ maxqF,
                                                 unsigned char* __restrict__ maxqG){
  __shared__ __align__(16) unsigned char orig[8192];
  __shared__ __align__(16) unsigned char sorted[8192];
  const int side = blockIdx.x >> 13;       // 0: zq (cols=y), 1: zqT (cols=x)
  const int row  = blockIdx.x & 8191;
  unsigned char* z = side ? zqT : zq;
  const int* srcC  = side ? srcF : srcG;
  unsigned char* mq = side ? maxqG : maxqF;
  unsigned char* zr = z + (size_t)row * N;
  const int t = threadIdx.x;
  #pragma unroll
  for (int k = 0; k < 2; ++k)
    *(uint4*)(orig + t * 16 + k * 4096) = *(const uint4*)(zr + t * 16 + k * 4096);
  __syncthreads();
  #pragma unroll
  for (int k = 0; k < 8; ++k){
    const int d = t + k * 256;             // dword 0..2047
    const int4 sc = *(const int4*)(srcC + d * 4);
    unsigned b0 = orig[sc.x], b1 = orig[sc.y], b2 = orig[sc.z], b3 = orig[sc.w];
    *(unsigned*)(sorted + d * 4) = b0 | (b1 << 8) | (b2 << 16) | (b3 << 24);
  }
  __syncthreads();
  #pragma unroll
  for (int k = 0; k < 2; ++k)
    *(uint4*)(zr + t * 16 + k * 4096) = *(const uint4*)(sorted + t * 16 + k * 4096);
  if (t < 128){
    const unsigned char* p = sorted + t * 64;
    unsigned mx = 0;
    #pragma unroll
    for (int d = 0; d < 16; ++d){
      unsigned u = *(const unsigned*)(p + d * 4);
      unsigned a = u & 255u, b = (u >> 8) & 255u, c = (u >> 16) & 255u, e = u >> 24;
      mx = mx > a ? mx : a; mx = mx > b ? mx : b;
      mx = mx > c ? mx : c; mx = mx > e ? mx : e;
    }
    mq[(size_t)row * 128 + t] = (unsigned char)mx;
  }
}

// ---------------------------------------------------------------------------
// repackd: gather duals/pmax/x2/y2 into sorted space; seed gmax buffer 6
// with chunk maxes of gts_p.
// ---------------------------------------------------------------------------
__global__ __launch_bounds__(256) void repackd_k(const int* __restrict__ srcF, const int* __restrict__ srcG,
    const float* __restrict__ fts, const float* __restrict__ gts,
    const float* __restrict__ pmaxF, const float* __restrict__ pmaxG,
    const float* __restrict__ x2, const float* __restrict__ y2,
    float* __restrict__ fts_p, float* __restrict__ gts_p,
    float* __restrict__ pmaxF_p, float* __restrict__ pmaxG_p,
    float* __restrict__ x2p, float* __restrict__ y2p,
    unsigned* __restrict__ gmax6){
  const int r = blockIdx.x * 256 + threadIdx.x;   // grid 32
  const int sf = srcF[r], sg = srcG[r];
  fts_p[r] = fts[sf]; pmaxF_p[r] = pmaxF[sf]; x2p[r] = x2[sf];
  const float gv = gts[sg];
  gts_p[r] = gv; pmaxG_p[r] = pmaxG[sg]; y2p[r] = y2[sg];
  atomicMax(gmax6 + (r >> 6), fkey(gv));
}

// ---------------------------------------------------------------------------
// sweeps: chunk-skipping premax sweep (sorted space). 1 row/wave.
// Bound: maxq[prow][c]*ZS + chunkmax(din)[c] > M - CUT  (tight: din sorted).
// Survivors compacted to LDS list (ballot prefix, deterministic), processed
// in groups of 8 (MLP). s = sum 2^(t-M), lse = M + lg2(s).
// MODE 0: dout[r] = 13 - lse - BIAS ; pmax_out[r] = lse ; atomicMax gmax_out
// MODE 1: contrib[r] = (fprev_true*ln2 + x2)*2^(fprev_true + lse - 26)
// ---------------------------------------------------------------------------
template<int MODE>
__global__ __launch_bounds__(256, 8) void sweeps_k(
    const unsigned char* __restrict__ z,
    const unsigned char* __restrict__ maxq,
    const int* __restrict__ srcRow,
    const float* __restrict__ din,
    const unsigned* __restrict__ gmax_in,
    float* __restrict__ dout,
    unsigned* __restrict__ gmax_out,
    const float* __restrict__ pmax_in,
    float* __restrict__ pmax_out,
    const float* __restrict__ fprev,
    const float* __restrict__ x2,
    float* __restrict__ contrib,
    float CUT){
  __shared__ unsigned short lists[4][128];
  const int w = threadIdx.x >> 6, l = threadIdx.x & 63;
  const int r = blockIdx.x * 4 + w;
  const int prow = srcRow[r];
  const float M = pmax_in[r];
  const unsigned char* mqp = maxq + (size_t)prow * 128;
  const float thr = M - CUT;
  const float b0 = __builtin_fmaf((float)mqp[l],      ZS, fdec(gmax_in[l]));
  const float b1 = __builtin_fmaf((float)mqp[l + 64], ZS, fdec(gmax_in[l + 64]));
  const bool sv0 = b0 > thr, sv1 = b1 > thr;
  const unsigned long long m0 = __ballot(sv0), m1 = __ballot(sv1);
  const int S0 = __popcll(m0);
  int S = S0 + __popcll(m1);
  const unsigned long long low = (1ull << l) - 1ull;
  if (sv0) lists[w][__popcll(m0 & low)] = (unsigned short)l;
  if (sv1) lists[w][S0 + __popcll(m1 & low)] = (unsigned short)(l + 64);
  if (S == 0){ if (l == 0) lists[w][0] = 0; S = 1; }
  const unsigned char* zr = z + (size_t)prow * N + l;
  const float* dg = din + l;
  float s = 0.f;
  for (int k = 0; k < S; k += 8){
    unsigned q0[8]; float g0[8];
    #pragma unroll
    for (int j = 0; j < 8; ++j){
      int kk = k + j; kk = kk < S ? kk : S - 1;
      const int c = ((int)lists[w][kk]) << 6;
      q0[j] = zr[c];
      g0[j] = dg[c];
    }
    #pragma unroll
    for (int j = 0; j < 8; ++j){
      float t = __builtin_fmaf((float)q0[j], ZS, g0[j] - M);
      float e = ex2(t);
      s += (k + j < S) ? e : 0.f;
    }
  }
  #pragma unroll
  for (int off = 32; off > 0; off >>= 1) s += __shfl_down(s, off);
  if (l == 0){
    const float lse = M + lg2(s);
    if (MODE == 0){
      const float dv = 13.0f - lse - BIAS;
      dout[r] = dv;
      pmax_out[r] = lse;
      atomicMax(gmax_out + (r >> 6), fkey(dv));
    } else {
      const float fti = fprev[r] + BIAS;    // true FtL
      const float rr = ex2(fti + lse - 26.0f);
      contrib[r] = (fti * LN2 + x2[r]) * rr;
    }
  }
}

// ---------------------------------------------------------------------------
// finish: value = sum(contrib) + mean_j((gts_j+BIAS)*ln2 + y2_j); out = sqrt
// ---------------------------------------------------------------------------
__global__ __launch_bounds__(256) void finish_k(const float* __restrict__ contrib,
                                                const float* __restrict__ gts,
                                                const float* __restrict__ y2,
                                                float* __restrict__ out){
  __shared__ float s1[256], s2[256];
  const int t = threadIdx.x;
  float a = 0.f, b = 0.f;
  for (int j = t; j < N; j += 256){ a += contrib[j]; b += (gts[j] + BIAS) * LN2 + y2[j]; }
  s1[t] = a; s2[t] = b; __syncthreads();
  for (int st = 128; st > 0; st >>= 1){
    if (t < st){ s1[t] += s1[t + st]; s2[t] += s2[t + st]; }
    __syncthreads();
  }
  if (t == 0) out[0] = sqrtf(s1[0] + s2[0] * (1.0f / (float)N));
}

// ---------------------------------------------------------------------------
extern "C" void kernel_launch(void* const* d_in, const int* in_sizes, int n_in,
                              void* d_out, int out_size, void* d_ws, size_t ws_size,
                              hipStream_t stream){
  const float* x = (const float*)d_in[0];
  const float* y = (const float*)d_in[1];
  float* out = (float*)d_out;
  char* ws = (char*)d_ws;

  // workspace layout (bytes)
  unsigned char* zq    = (unsigned char*)(ws);              // 64 MiB
  unsigned char* zqT   = (unsigned char*)(ws + 67108864);   // 64 MiB
  u16*   xb     = (u16*)  (ws + 134217728);                 // 4 MiB
  u16*   yb     = (u16*)  (ws + 138412032);                 // 4 MiB
  unsigned char* maxqF = (unsigned char*)(ws + 142606336);  // 1 MiB
  unsigned char* maxqG = (unsigned char*)(ws + 143654912);  // 1 MiB
  char* fb = ws + 144703488;
  float* x2      = (float*)(fb);
  float* y2      = (float*)(fb + 32768);
  float* fts     = (float*)(fb + 65536);
  float* gts     = (float*)(fb + 98304);
  float* pmaxF   = (float*)(fb + 131072);
  float* pmaxG   = (float*)(fb + 163840);
  float* fts_p   = (float*)(fb + 196608);
  float* gts_p   = (float*)(fb + 229376);
  float* pmaxF_p = (float*)(fb + 262144);
  float* pmaxG_p = (float*)(fb + 294912);
  float* x2p     = (float*)(fb + 327680);
  float* y2p     = (float*)(fb + 360448);
  float* contrib = (float*)(fb + 393216);
  int*   srcF    = (int*)  (fb + 425984);
  int*   srcG    = (int*)  (fb + 458752);
  unsigned* gmax = (unsigned*)(fb + 491520);                // 104*128 uints

  zero_k<<<52, 256, 0, stream>>>(gmax);
  prep_k<<<4096, 256, 0, stream>>>(x, y, xb, yb, x2, y2, gts);
  gemm_k<<<dim3(64, 64), 256, 0, stream>>>(xb, yb, zq, zqT);
  // bootstrap: 3 full iterations with online max (seeds pmax, duals)
  for (int it = 0; it < 3; ++it){
    sweept_k<<<2048, 256, 0, stream>>>(zq,  gts, fts, pmaxF);
    sweept_k<<<2048, 256, 0, stream>>>(zqT, fts, gts, pmaxG);
  }
  // sort index spaces by current duals; repack z cols in place + maxq; duals
  rank_k<<<32, 256, 0, stream>>>(fts, srcF);
  rank_k<<<32, 256, 0, stream>>>(gts, srcG);
  repackz_k<<<16384, 256, 0, stream>>>(zq, zqT, srcG, srcF, maxqF, maxqG);
  repackd_k<<<32, 256, 0, stream>>>(srcF, srcG, fts, gts, pmaxF, pmaxG, x2, y2,
                                    fts_p, gts_p, pmaxF_p, pmaxG_p, x2p, y2p,
                                    gmax + 6 * 128);
  // fast chunk-skip iterations (47): sweep s reads gmax[s], writes gmax[s+1]
  for (int s = 6; s < 100; s += 2){
    const float cut = (s == 6) ? 70.0f : 45.0f;
    sweeps_k<0><<<2048, 256, 0, stream>>>(zq,  maxqF, srcF, gts_p, gmax + s * 128,
                                          fts_p, gmax + (s + 1) * 128,
                                          pmaxF_p, pmaxF_p, nullptr, nullptr, nullptr, cut);
    sweeps_k<0><<<2048, 256, 0, stream>>>(zqT, maxqG, srcG, fts_p, gmax + (s + 1) * 128,
                                          gts_p, gmax + (s + 2) * 128,
                                          pmaxG_p, pmaxG_p, nullptr, nullptr, nullptr, cut);
  }
  // final value pass (f-side) + reduction
  sweeps_k<1><<<2048, 256, 0, stream>>>(zq, maxqF, srcF, gts_p, gmax + 100 * 128,
                                        nullptr, nullptr, pmaxF_p, nullptr,
                                        fts_p, x2p, contrib, 45.0f);
  finish_k<<<1, 256, 0, stream>>>(contrib, gts_p, y2p, out);
}

// Round 8
// 3622.525 us; speedup vs baseline: 1.2074x; 1.2074x over previous
//
#include <hip/hip_runtime.h>

#define N 8192
#define DK 256
#define LOG2E 1.4426950408889634f
#define LN2   0.6931471805599453f
#define ZS    2.5f            // int8 dequant scale (Zl = q * ZS)
#define QS    1.1541560327f   // 2*log2e / ZS  (fp32 acc -> q units)
#define BIAS  320.0f          // 128 * ZS ; duals stored shifted by -BIAS
// log2(8192) = 13 exactly; (loga+logb) in log2 units = -26

typedef unsigned short u16;
typedef u16   ushort8 __attribute__((ext_vector_type(8)));
typedef __bf16 bf16x8 __attribute__((ext_vector_type(8)));
typedef float  f32x4  __attribute__((ext_vector_type(4)));

__device__ __forceinline__ u16 f2bf(float f){
  unsigned u = __builtin_bit_cast(unsigned, f);
  return (u16)((u + 0x7fffu + ((u >> 16) & 1u)) >> 16);   // RNE fp32->bf16
}
__device__ __forceinline__ float ex2(float x){            // v_exp_f32 = 2^x
  float r; asm("v_exp_f32 %0, %1" : "=v"(r) : "v"(x)); return r;
}
__device__ __forceinline__ float lg2(float x){            // v_log_f32 = log2(x)
  float r; asm("v_log_f32 %0, %1" : "=v"(r) : "v"(x)); return r;
}
__device__ __forceinline__ float cub0(unsigned u){ float r; asm("v_cvt_f32_ubyte0 %0, %1":"=v"(r):"v"(u)); return r; }
__device__ __forceinline__ float cub1(unsigned u){ float r; asm("v_cvt_f32_ubyte1 %0, %1":"=v"(r):"v"(u)); return r; }
__device__ __forceinline__ float cub2(unsigned u){ float r; asm("v_cvt_f32_ubyte2 %0, %1":"=v"(r):"v"(u)); return r; }
__device__ __forceinline__ float cub3(unsigned u){ float r; asm("v_cvt_f32_ubyte3 %0, %1":"=v"(r):"v"(u)); return r; }

// monotone float <-> uint key (for atomicMax on floats of any sign)
__device__ __forceinline__ unsigned fkey(float f){
  unsigned b = __float_as_uint(f);
  return (b & 0x80000000u) ? ~b : (b | 0x80000000u);
}
__device__ __forceinline__ float fdec(unsigned k){
  unsigned b = (k & 0x80000000u) ? (k ^ 0x80000000u) : ~k;
  return __uint_as_float(b);
}

// ---------------------------------------------------------------------------
// prep: row sum-of-squares + bf16 copies + init gts = -y2*LOG2E - BIAS (g0=0)
// ---------------------------------------------------------------------------
__global__ __launch_bounds__(256) void prep_k(const float* __restrict__ x, const float* __restrict__ y,
                                              u16* __restrict__ xb, u16* __restrict__ yb,
                                              float* __restrict__ x2, float* __restrict__ y2,
                                              float* __restrict__ gts){
  const int w = threadIdx.x >> 6, l = threadIdx.x & 63;
  const int r = blockIdx.x * 4 + w;         // 0..16383
  const bool isx = r < N;
  const int rr = isx ? r : r - N;
  const float* src = (isx ? x : y) + (size_t)rr * DK;
  float4 v = *(const float4*)(src + l * 4);
  ushort4 bv;
  bv.x = f2bf(v.x); bv.y = f2bf(v.y); bv.z = f2bf(v.z); bv.w = f2bf(v.w);
  *(ushort4*)((isx ? xb : yb) + (size_t)rr * DK + l * 4) = bv;
  float p = v.x*v.x + v.y*v.y + v.z*v.z + v.w*v.w;
  #pragma unroll
  for (int off = 32; off > 0; off >>= 1) p += __shfl_down(p, off);
  if (l == 0){
    if (isx) x2[rr] = p;
    else { y2[rr] = p; gts[rr] = -p * LOG2E - BIAS; }
  }
}

// ---------------------------------------------------------------------------
// zero_k: zero the gmax key buffers (must happen every call, before use)
// ---------------------------------------------------------------------------
__global__ __launch_bounds__(256) void zero_k(unsigned* __restrict__ g){
  g[blockIdx.x * 256 + threadIdx.x] = 0u;
}

// ---------------------------------------------------------------------------
// gemm: z = xb*yb^T (bf16 MFMA). Quantize Zl = 2*log2e*z to biased uint8,
// stage tiles in LDS, store zq and zqT coalesced dwordx4.
// ---------------------------------------------------------------------------
__global__ __launch_bounds__(256) void gemm_k(const u16* __restrict__ xb, const u16* __restrict__ yb,
                                              unsigned char* __restrict__ zq,
                                              unsigned char* __restrict__ zqT){
  __shared__ __align__(16) u16 As[128 * 72];
  __shared__ __align__(16) u16 Bs[128 * 72];
  const int t = threadIdx.x;
  const int w = t >> 6, l = t & 63;
  const int wm = w >> 1, wn = w & 1;
  const int brow = blockIdx.y * 128, bcol = blockIdx.x * 128;
  const int tr = t >> 3, tc = t & 7;
  f32x4 acc[4][4] = {};
  for (int ks = 0; ks < 4; ++ks){
    #pragma unroll
    for (int rr = 0; rr < 4; ++rr){
      const int row = tr + rr * 32;
      *(ushort8*)&As[row * 72 + tc * 8] = *(const ushort8*)&xb[(size_t)(brow + row) * DK + ks * 64 + tc * 8];
      *(ushort8*)&Bs[row * 72 + tc * 8] = *(const ushort8*)&yb[(size_t)(bcol + row) * DK + ks * 64 + tc * 8];
    }
    __syncthreads();
    #pragma unroll
    for (int kk = 0; kk < 2; ++kk){
      bf16x8 av[4], bv[4];
      #pragma unroll
      for (int mi = 0; mi < 4; ++mi){
        const int ar = wm * 64 + mi * 16 + (l & 15);
        av[mi] = __builtin_bit_cast(bf16x8, *(const ushort8*)&As[ar * 72 + kk * 32 + (l >> 4) * 8]);
      }
      #pragma unroll
      for (int ni = 0; ni < 4; ++ni){
        const int br = wn * 64 + ni * 16 + (l & 15);
        bv[ni] = __builtin_bit_cast(bf16x8, *(const ushort8*)&Bs[br * 72 + kk * 32 + (l >> 4) * 8]);
      }
      #pragma unroll
      for (int mi = 0; mi < 4; ++mi)
        #pragma unroll
        for (int ni = 0; ni < 4; ++ni)
          acc[mi][ni] = __builtin_amdgcn_mfma_f32_16x16x32_bf16(av[mi], bv[ni], acc[mi][ni], 0, 0, 0);
    }
    __syncthreads();
  }
  // quantize: Cs row-major [128][128]; Ct col-major [col][row] stride 144
  unsigned char* Cs = (unsigned char*)As;
  unsigned char* Ct = (unsigned char*)Bs;
  #pragma unroll
  for (int mi = 0; mi < 4; ++mi){
    const int rowb = wm * 64 + mi * 16 + (l >> 4) * 4;
    #pragma unroll
    for (int ni = 0; ni < 4; ++ni){
      const int col = wn * 64 + ni * 16 + (l & 15);
      unsigned pk = 0;
      #pragma unroll
      for (int rr = 0; rr < 4; ++rr){
        float q = fminf(fmaxf(acc[mi][ni][rr] * QS, -127.f), 127.f);
        unsigned b = (unsigned)((int)__builtin_rintf(q) + 128) & 255u;
        Cs[(rowb + rr) * 128 + col] = (unsigned char)b;
        pk |= b << (8 * rr);
      }
      *(unsigned*)(Ct + col * 144 + rowb) = pk;
    }
  }
  __syncthreads();
  const int trow0 = t >> 3, kseg = t & 7;
  #pragma unroll
  for (int ii = 0; ii < 4; ++ii){
    const int row = trow0 + ii * 32;
    int4 v = *(const int4*)(Cs + row * 128 + kseg * 16);
    *(int4*)(zq + (size_t)(brow + row) * N + bcol + kseg * 16) = v;
    int4 vt = *(const int4*)(Ct + row * 144 + kseg * 16);
    *(int4*)(zqT + (size_t)(bcol + row) * N + brow + kseg * 16) = vt;
  }
}

// ---------------------------------------------------------------------------
// sweept: bootstrap sweep with full online-max tracking (1 row/wave).
// Also stores pmax_out[i] = lse2 for the premax kernels.
// ---------------------------------------------------------------------------
__global__ __launch_bounds__(256) void sweept_k(const unsigned char* __restrict__ z,
                                                const float* __restrict__ din,
                                                float* __restrict__ dout,
                                                float* __restrict__ pmax_out){
  const int w = threadIdx.x >> 6, l = threadIdx.x & 63;
  const int i = blockIdx.x * 4 + w;
  const unsigned char* zr = z + (size_t)i * N + l * 16;
  float m = -1e30f, s = 0.f;
  uint4 zA = *(const uint4*)(zr);
  #pragma unroll
  for (int it = 0; it < 8; ++it){
    uint4 zB = zA;
    if (it < 7) zB = *(const uint4*)(zr + (it + 1) * 1024);
    const float* gp = din + it * 1024 + l * 16;
    const float4 g0 = *(const float4*)(gp);
    const float4 g1 = *(const float4*)(gp + 4);
    const float4 g2 = *(const float4*)(gp + 8);
    const float4 g3 = *(const float4*)(gp + 12);
    float tt[16];
    tt[0]  = __builtin_fmaf(cub0(zA.x), ZS, g0.x);
    tt[1]  = __builtin_fmaf(cub1(zA.x), ZS, g0.y);
    tt[2]  = __builtin_fmaf(cub2(zA.x), ZS, g0.z);
    tt[3]  = __builtin_fmaf(cub3(zA.x), ZS, g0.w);
    tt[4]  = __builtin_fmaf(cub0(zA.y), ZS, g1.x);
    tt[5]  = __builtin_fmaf(cub1(zA.y), ZS, g1.y);
    tt[6]  = __builtin_fmaf(cub2(zA.y), ZS, g1.z);
    tt[7]  = __builtin_fmaf(cub3(zA.y), ZS, g1.w);
    tt[8]  = __builtin_fmaf(cub0(zA.z), ZS, g2.x);
    tt[9]  = __builtin_fmaf(cub1(zA.z), ZS, g2.y);
    tt[10] = __builtin_fmaf(cub2(zA.z), ZS, g2.z);
    tt[11] = __builtin_fmaf(cub3(zA.z), ZS, g2.w);
    tt[12] = __builtin_fmaf(cub0(zA.w), ZS, g3.x);
    tt[13] = __builtin_fmaf(cub1(zA.w), ZS, g3.y);
    tt[14] = __builtin_fmaf(cub2(zA.w), ZS, g3.z);
    tt[15] = __builtin_fmaf(cub3(zA.w), ZS, g3.w);
    float a0 = fmaxf(tt[0], tt[1]),  a1 = fmaxf(tt[2], tt[3]);
    float a2 = fmaxf(tt[4], tt[5]),  a3 = fmaxf(tt[6], tt[7]);
    float a4 = fmaxf(tt[8], tt[9]),  a5 = fmaxf(tt[10], tt[11]);
    float a6 = fmaxf(tt[12], tt[13]), a7 = fmaxf(tt[14], tt[15]);
    float b0 = fmaxf(a0, a1), b1 = fmaxf(a2, a3), b2 = fmaxf(a4, a5), b3 = fmaxf(a6, a7);
    float nm = fmaxf(fmaxf(fmaxf(b0, b1), fmaxf(b2, b3)), m);
    float s0 = ex2(tt[0] - nm) + ex2(tt[1] - nm) + ex2(tt[2] - nm) + ex2(tt[3] - nm)
             + ex2(tt[4] - nm) + ex2(tt[5] - nm) + ex2(tt[6] - nm) + ex2(tt[7] - nm);
    float s1 = ex2(tt[8] - nm) + ex2(tt[9] - nm) + ex2(tt[10] - nm) + ex2(tt[11] - nm)
             + ex2(tt[12] - nm) + ex2(tt[13] - nm) + ex2(tt[14] - nm) + ex2(tt[15] - nm);
    s = __builtin_fmaf(s, ex2(m - nm), s0 + s1);
    m = nm;
    zA = zB;
  }
  #pragma unroll
  for (int off = 32; off > 0; off >>= 1){
    float om = __shfl_down(m, off);
    float os = __shfl_down(s, off);
    float nm = fmaxf(m, om);
    s = __builtin_fmaf(s, ex2(m - nm), os * ex2(om - nm));
    m = nm;
  }
  if (l == 0){
    float lse2 = m + lg2(s);          // true lse2 (bias cancels)
    dout[i] = 13.0f - lse2 - BIAS;
    pmax_out[i] = lse2;
  }
}

// ---------------------------------------------------------------------------
// rank2_k: exact deterministic rank (ties by index), BOTH sides in one
// launch. One wave per element; keys staged in LDS. Grid 4096 x 256.
// blocks 0..2047 -> fts/srcF ; 2048..4095 -> gts/srcG.
// ---------------------------------------------------------------------------
__global__ __launch_bounds__(256) void rank2_k(const float* __restrict__ fts,
                                               const float* __restrict__ gts,
                                               int* __restrict__ srcF,
                                               int* __restrict__ srcG){
  __shared__ __align__(16) float kl[8192];
  const int side = blockIdx.x >> 11;
  const float* key = side ? gts : fts;
  for (int i = threadIdx.x; i < 2048; i += 256)
    *(float4*)(kl + i * 4) = *(const float4*)(key + i * 4);
  __syncthreads();
  const int w = threadIdx.x >> 6, l = threadIdx.x & 63;
  const int j = (blockIdx.x & 2047) * 4 + w;   // 0..8191
  const float v = kl[j];
  int r = 0;
  #pragma unroll 4
  for (int ii = 0; ii < 32; ++ii){
    const int base = ii * 256 + l * 4;
    const float4 k4 = *(const float4*)(kl + base);
    r += (k4.x < v) || (k4.x == v && (base + 0) < j);
    r += (k4.y < v) || (k4.y == v && (base + 1) < j);
    r += (k4.z < v) || (k4.z == v && (base + 2) < j);
    r += (k4.w < v) || (k4.w == v && (base + 3) < j);
  }
  #pragma unroll
  for (int off = 32; off > 0; off >>= 1) r += __shfl_down(r, off);
  if (l == 0) (side ? srcG : srcF)[r] = j;
}

// ---------------------------------------------------------------------------
// repackz: in-place column permutation of zq (cols by srcG) and zqT (cols by
// srcF), one block per physical row; also emits per-(row,64-chunk) max byte.
// Rows stay physical (sweeps indirect via srcRow).
// ---------------------------------------------------------------------------
__global__ __launch_bounds__(256) void repackz_k(unsigned char* __restrict__ zq,
                                                 unsigned char* __restrict__ zqT,
                                                 const int* __restrict__ srcG,
                                                 const int* __restrict__ srcF,
                                                 unsigned char* __restrict__ maxqF,
                                                 unsigned char* __restrict__ maxqG){
  __shared__ __align__(16) unsigned char orig[8192];
  __shared__ __align__(16) unsigned char sorted[8192];
  const int side = blockIdx.x >> 13;       // 0: zq (cols=y), 1: zqT (cols=x)
  const int row  = blockIdx.x & 8191;
  unsigned char* z = side ? zqT : zq;
  const int* srcC  = side ? srcF : srcG;
  unsigned char* mq = side ? maxqG : maxqF;
  unsigned char* zr = z + (size_t)row * N;
  const int t = threadIdx.x;
  #pragma unroll
  for (int k = 0; k < 2; ++k)
    *(uint4*)(orig + t * 16 + k * 4096) = *(const uint4*)(zr + t * 16 + k * 4096);
  __syncthreads();
  #pragma unroll
  for (int k = 0; k < 8; ++k){
    const int d = t + k * 256;             // dword 0..2047
    const int4 sc = *(const int4*)(srcC + d * 4);
    unsigned b0 = orig[sc.x], b1 = orig[sc.y], b2 = orig[sc.z], b3 = orig[sc.w];
    *(unsigned*)(sorted + d * 4) = b0 | (b1 << 8) | (b2 << 16) | (b3 << 24);
  }
  __syncthreads();
  #pragma unroll
  for (int k = 0; k < 2; ++k)
    *(uint4*)(zr + t * 16 + k * 4096) = *(const uint4*)(sorted + t * 16 + k * 4096);
  if (t < 128){
    const unsigned char* p = sorted + t * 64;
    unsigned mx = 0;
    #pragma unroll
    for (int d = 0; d < 16; ++d){
      unsigned u = *(const unsigned*)(p + d * 4);
      unsigned a = u & 255u, b = (u >> 8) & 255u, c = (u >> 16) & 255u, e = u >> 24;
      mx = mx > a ? mx : a; mx = mx > b ? mx : b;
      mx = mx > c ? mx : c; mx = mx > e ? mx : e;
    }
    mq[(size_t)row * 128 + t] = (unsigned char)mx;
  }
}

// ---------------------------------------------------------------------------
// repackd: gather duals/pmax/x2/y2 into sorted space; seed gmax buffer 4
// with chunk maxes of gts_p.
// ---------------------------------------------------------------------------
__global__ __launch_bounds__(256) void repackd_k(const int* __restrict__ srcF, const int* __restrict__ srcG,
    const float* __restrict__ fts, const float* __restrict__ gts,
    const float* __restrict__ pmaxF, const float* __restrict__ pmaxG,
    const float* __restrict__ x2, const float* __restrict__ y2,
    float* __restrict__ fts_p, float* __restrict__ gts_p,
    float* __restrict__ pmaxF_p, float* __restrict__ pmaxG_p,
    float* __restrict__ x2p, float* __restrict__ y2p,
    unsigned* __restrict__ gmax4){
  const int r = blockIdx.x * 256 + threadIdx.x;   // grid 32
  const int sf = srcF[r], sg = srcG[r];
  fts_p[r] = fts[sf]; pmaxF_p[r] = pmaxF[sf]; x2p[r] = x2[sf];
  const float gv = gts[sg];
  gts_p[r] = gv; pmaxG_p[r] = pmaxG[sg]; y2p[r] = y2[sg];
  atomicMax(gmax4 + (r >> 6), fkey(gv));
}

// ---------------------------------------------------------------------------
// sweeps: chunk-skipping premax sweep (sorted space). 1 row/wave.
// Bound: maxq[prow][c]*ZS + chunkmax(din)[c] > M - CUT  (tight: din sorted).
// Survivors compacted to LDS list (ballot prefix, deterministic). Processed
// 4 chunks/iteration: lane l handles dword (l&15) of chunk list[k + (l>>4)]
// -> 1 dword z-load + 1 float4 dual-load per lane-iter (no byte loads).
// MODE 0: dout[r] = 13 - lse - BIAS ; pmax_out[r] = lse ; atomicMax gmax_out
// MODE 1: contrib[r] = (fprev_true*ln2 + x2)*2^(fprev_true + lse - 26)
// ---------------------------------------------------------------------------
template<int MODE>
__global__ __launch_bounds__(256) void sweeps_k(
    const unsigned char* __restrict__ z,
    const unsigned char* __restrict__ maxq,
    const int* __restrict__ srcRow,
    const float* __restrict__ din,
    const unsigned* __restrict__ gmax_in,
    float* __restrict__ dout,
    unsigned* __restrict__ gmax_out,
    const float* __restrict__ pmax_in,
    float* __restrict__ pmax_out,
    const float* __restrict__ fprev,
    const float* __restrict__ x2,
    float* __restrict__ contrib,
    float CUT){
  __shared__ unsigned short lists[4][128];
  const int w = threadIdx.x >> 6, l = threadIdx.x & 63;
  const int r = blockIdx.x * 4 + w;
  const int prow = srcRow[r];
  const float M = pmax_in[r];
  const unsigned char* mqp = maxq + (size_t)prow * 128;
  const float thr = M - CUT;
  const float b0 = __builtin_fmaf((float)mqp[l],      ZS, fdec(gmax_in[l]));
  const float b1 = __builtin_fmaf((float)mqp[l + 64], ZS, fdec(gmax_in[l + 64]));
  const bool sv0 = b0 > thr, sv1 = b1 > thr;
  const unsigned long long m0 = __ballot(sv0), m1 = __ballot(sv1);
  const int S0 = __popcll(m0);
  int S = S0 + __popcll(m1);
  const unsigned long long low = (1ull << l) - 1ull;
  if (sv0) lists[w][__popcll(m0 & low)] = (unsigned short)l;
  if (sv1) lists[w][S0 + __popcll(m1 & low)] = (unsigned short)(l + 64);
  if (S == 0){ if (l == 0) lists[w][0] = 0; S = 1; }
  const unsigned* zr4 = (const unsigned*)(z + (size_t)prow * N);
  const int sub = l >> 4, q16 = l & 15;
  float s = 0.f;
  #pragma unroll 2
  for (int k = 0; k < S; k += 4){
    int kk = k + sub;
    const bool act = kk < S;
    kk = act ? kk : S - 1;
    const int c = (int)lists[w][kk];
    const unsigned zd = zr4[c * 16 + q16];
    const float4 gv = *(const float4*)(din + (c << 6) + (q16 << 2));
    const float t0 = __builtin_fmaf(cub0(zd), ZS, gv.x - M);
    const float t1 = __builtin_fmaf(cub1(zd), ZS, gv.y - M);
    const float t2 = __builtin_fmaf(cub2(zd), ZS, gv.z - M);
    const float t3 = __builtin_fmaf(cub3(zd), ZS, gv.w - M);
    const float e = (ex2(t0) + ex2(t1)) + (ex2(t2) + ex2(t3));
    s += act ? e : 0.f;
  }
  #pragma unroll
  for (int off = 32; off > 0; off >>= 1) s += __shfl_down(s, off);
  if (l == 0){
    const float lse = M + lg2(s);
    if (MODE == 0){
      const float dv = 13.0f - lse - BIAS;
      dout[r] = dv;
      pmax_out[r] = lse;
      atomicMax(gmax_out + (r >> 6), fkey(dv));
    } else {
      const float fti = fprev[r] + BIAS;    // true FtL
      const float rr = ex2(fti + lse - 26.0f);
      contrib[r] = (fti * LN2 + x2[r]) * rr;
    }
  }
}

// ---------------------------------------------------------------------------
// finish: value = sum(contrib) + mean_j((gts_j+BIAS)*ln2 + y2_j); out = sqrt
// ---------------------------------------------------------------------------
__global__ __launch_bounds__(256) void finish_k(const float* __restrict__ contrib,
                                                const float* __restrict__ gts,
                                                const float* __restrict__ y2,
                                                float* __restrict__ out){
  __shared__ float s1[256], s2[256];
  const int t = threadIdx.x;
  float a = 0.f, b = 0.f;
  for (int j = t; j < N; j += 256){ a += contrib[j]; b += (gts[j] + BIAS) * LN2 + y2[j]; }
  s1[t] = a; s2[t] = b; __syncthreads();
  for (int st = 128; st > 0; st >>= 1){
    if (t < st){ s1[t] += s1[t + st]; s2[t] += s2[t + st]; }
    __syncthreads();
  }
  if (t == 0) out[0] = sqrtf(s1[0] + s2[0] * (1.0f / (float)N));
}

// ---------------------------------------------------------------------------
extern "C" void kernel_launch(void* const* d_in, const int* in_sizes, int n_in,
                              void* d_out, int out_size, void* d_ws, size_t ws_size,
                              hipStream_t stream){
  const float* x = (const float*)d_in[0];
  const float* y = (const float*)d_in[1];
  float* out = (float*)d_out;
  char* ws = (char*)d_ws;

  // workspace layout (bytes)
  unsigned char* zq    = (unsigned char*)(ws);              // 64 MiB
  unsigned char* zqT   = (unsigned char*)(ws + 67108864);   // 64 MiB
  u16*   xb     = (u16*)  (ws + 134217728);                 // 4 MiB
  u16*   yb     = (u16*)  (ws + 138412032);                 // 4 MiB
  unsigned char* maxqF = (unsigned char*)(ws + 142606336);  // 1 MiB
  unsigned char* maxqG = (unsigned char*)(ws + 143654912);  // 1 MiB
  char* fb = ws + 144703488;
  float* x2      = (float*)(fb);
  float* y2      = (float*)(fb + 32768);
  float* fts     = (float*)(fb + 65536);
  float* gts     = (float*)(fb + 98304);
  float* pmaxF   = (float*)(fb + 131072);
  float* pmaxG   = (float*)(fb + 163840);
  float* fts_p   = (float*)(fb + 196608);
  float* gts_p   = (float*)(fb + 229376);
  float* pmaxF_p = (float*)(fb + 262144);
  float* pmaxG_p = (float*)(fb + 294912);
  float* x2p     = (float*)(fb + 327680);
  float* y2p     = (float*)(fb + 360448);
  float* contrib = (float*)(fb + 393216);
  int*   srcF    = (int*)  (fb + 425984);
  int*   srcG    = (int*)  (fb + 458752);
  unsigned* gmax = (unsigned*)(fb + 491520);                // 104*128 uints

  zero_k<<<52, 256, 0, stream>>>(gmax);
  prep_k<<<4096, 256, 0, stream>>>(x, y, xb, yb, x2, y2, gts);
  gemm_k<<<dim3(64, 64), 256, 0, stream>>>(xb, yb, zq, zqT);
  // bootstrap: 2 full iterations with online max (seeds pmax, duals)
  for (int it = 0; it < 2; ++it){
    sweept_k<<<2048, 256, 0, stream>>>(zq,  gts, fts, pmaxF);
    sweept_k<<<2048, 256, 0, stream>>>(zqT, fts, gts, pmaxG);
  }
  // sort index spaces by current duals; repack z cols in place + maxq; duals
  rank2_k<<<4096, 256, 0, stream>>>(fts, gts, srcF, srcG);
  repackz_k<<<16384, 256, 0, stream>>>(zq, zqT, srcG, srcF, maxqF, maxqG);
  repackd_k<<<32, 256, 0, stream>>>(srcF, srcG, fts, gts, pmaxF, pmaxG, x2, y2,
                                    fts_p, gts_p, pmaxF_p, pmaxG_p, x2p, y2p,
                                    gmax + 4 * 128);
  // fast chunk-skip iterations (48): sweep s reads gmax[s], writes gmax[s+1]
  for (int s = 4; s < 100; s += 2){
    const float cut = (s == 4) ? 70.0f : 45.0f;
    sweeps_k<0><<<2048, 256, 0, stream>>>(zq,  maxqF, srcF, gts_p, gmax + s * 128,
                                          fts_p, gmax + (s + 1) * 128,
                                          pmaxF_p, pmaxF_p, nullptr, nullptr, nullptr, cut);
    sweeps_k<0><<<2048, 256, 0, stream>>>(zqT, maxqG, srcG, fts_p, gmax + (s + 1) * 128,
                                          gts_p, gmax + (s + 2) * 128,
                                          pmaxG_p, pmaxG_p, nullptr, nullptr, nullptr, cut);
  }
  // final value pass (f-side) + reduction
  sweeps_k<1><<<2048, 256, 0, stream>>>(zq, maxqF, srcF, gts_p, gmax + 100 * 128,
                                        nullptr, nullptr, pmaxF_p, nullptr,
                                        fts_p, x2p, contrib, 45.0f);
  finish_k<<<1, 256, 0, stream>>>(contrib, gts_p, y2p, out);
}

// Round 9
// 3093.367 us; speedup vs baseline: 1.4140x; 1.1711x over previous
//
#include <hip/hip_runtime.h>

#define N 8192
#define DK 256
#define LOG2E 1.4426950408889634f
#define LN2   0.6931471805599453f
#define ZS    2.5f            // int8 dequant scale (Zl = q * ZS)
#define QS    1.1541560327f   // 2*log2e / ZS  (fp32 acc -> q units)
#define BIAS  320.0f          // 128 * ZS ; duals stored shifted by -BIAS
// log2(8192) = 13 exactly; (loga+logb) in log2 units = -26

typedef unsigned short u16;
typedef u16   ushort8 __attribute__((ext_vector_type(8)));
typedef __bf16 bf16x8 __attribute__((ext_vector_type(8)));
typedef float  f32x4  __attribute__((ext_vector_type(4)));

__device__ __forceinline__ u16 f2bf(float f){
  unsigned u = __builtin_bit_cast(unsigned, f);
  return (u16)((u + 0x7fffu + ((u >> 16) & 1u)) >> 16);   // RNE fp32->bf16
}
__device__ __forceinline__ float ex2(float x){            // v_exp_f32 = 2^x
  float r; asm("v_exp_f32 %0, %1" : "=v"(r) : "v"(x)); return r;
}
__device__ __forceinline__ float lg2(float x){            // v_log_f32 = log2(x)
  float r; asm("v_log_f32 %0, %1" : "=v"(r) : "v"(x)); return r;
}
__device__ __forceinline__ float cub0(unsigned u){ float r; asm("v_cvt_f32_ubyte0 %0, %1":"=v"(r):"v"(u)); return r; }
__device__ __forceinline__ float cub1(unsigned u){ float r; asm("v_cvt_f32_ubyte1 %0, %1":"=v"(r):"v"(u)); return r; }
__device__ __forceinline__ float cub2(unsigned u){ float r; asm("v_cvt_f32_ubyte2 %0, %1":"=v"(r):"v"(u)); return r; }
__device__ __forceinline__ float cub3(unsigned u){ float r; asm("v_cvt_f32_ubyte3 %0, %1":"=v"(r):"v"(u)); return r; }

// monotone float <-> uint key (for atomicMax on floats of any sign)
__device__ __forceinline__ unsigned fkey(float f){
  unsigned b = __float_as_uint(f);
  return (b & 0x80000000u) ? ~b : (b | 0x80000000u);
}
__device__ __forceinline__ float fdec(unsigned k){
  unsigned b = (k & 0x80000000u) ? (k ^ 0x80000000u) : ~k;
  return __uint_as_float(b);
}
__device__ __forceinline__ unsigned umax2(unsigned a, unsigned b){ return a > b ? a : b; }

// ---------------------------------------------------------------------------
// prep: row sum-of-squares + bf16 copies + init gts = -y2*LOG2E - BIAS (g0=0)
// ---------------------------------------------------------------------------
__global__ __launch_bounds__(256) void prep_k(const float* __restrict__ x, const float* __restrict__ y,
                                              u16* __restrict__ xb, u16* __restrict__ yb,
                                              float* __restrict__ x2, float* __restrict__ y2,
                                              float* __restrict__ gts){
  const int w = threadIdx.x >> 6, l = threadIdx.x & 63;
  const int r = blockIdx.x * 4 + w;         // 0..16383
  const bool isx = r < N;
  const int rr = isx ? r : r - N;
  const float* src = (isx ? x : y) + (size_t)rr * DK;
  float4 v = *(const float4*)(src + l * 4);
  ushort4 bv;
  bv.x = f2bf(v.x); bv.y = f2bf(v.y); bv.z = f2bf(v.z); bv.w = f2bf(v.w);
  *(ushort4*)((isx ? xb : yb) + (size_t)rr * DK + l * 4) = bv;
  float p = v.x*v.x + v.y*v.y + v.z*v.z + v.w*v.w;
  #pragma unroll
  for (int off = 32; off > 0; off >>= 1) p += __shfl_down(p, off);
  if (l == 0){
    if (isx) x2[rr] = p;
    else { y2[rr] = p; gts[rr] = -p * LOG2E - BIAS; }
  }
}

// ---------------------------------------------------------------------------
// zero_k: zero the gmax key buffers (every call, before use)
// ---------------------------------------------------------------------------
__global__ __launch_bounds__(256) void zero_k(unsigned* __restrict__ g){
  g[blockIdx.x * 256 + threadIdx.x] = 0u;
}

// ---------------------------------------------------------------------------
// gemm: z = xb*yb^T (bf16 MFMA). Quantize Zl = 2*log2e*z to biased uint8,
// store zq and zqT coalesced. Epilogue also computes per-(row, 64-col-chunk)
// max byte for BOTH sides fully in-register (fragment-local max + shfl_xor).
// ---------------------------------------------------------------------------
__global__ __launch_bounds__(256) void gemm_k(const u16* __restrict__ xb, const u16* __restrict__ yb,
                                              unsigned char* __restrict__ zq,
                                              unsigned char* __restrict__ zqT,
                                              unsigned char* __restrict__ maxqF,
                                              unsigned char* __restrict__ maxqG){
  __shared__ __align__(16) u16 As[128 * 72];
  __shared__ __align__(16) u16 Bs[128 * 72];
  const int t = threadIdx.x;
  const int w = t >> 6, l = t & 63;
  const int wm = w >> 1, wn = w & 1;
  const int brow = blockIdx.y * 128, bcol = blockIdx.x * 128;
  const int tr = t >> 3, tc = t & 7;
  f32x4 acc[4][4] = {};
  for (int ks = 0; ks < 4; ++ks){
    #pragma unroll
    for (int rr = 0; rr < 4; ++rr){
      const int row = tr + rr * 32;
      *(ushort8*)&As[row * 72 + tc * 8] = *(const ushort8*)&xb[(size_t)(brow + row) * DK + ks * 64 + tc * 8];
      *(ushort8*)&Bs[row * 72 + tc * 8] = *(const ushort8*)&yb[(size_t)(bcol + row) * DK + ks * 64 + tc * 8];
    }
    __syncthreads();
    #pragma unroll
    for (int kk = 0; kk < 2; ++kk){
      bf16x8 av[4], bv[4];
      #pragma unroll
      for (int mi = 0; mi < 4; ++mi){
        const int ar = wm * 64 + mi * 16 + (l & 15);
        av[mi] = __builtin_bit_cast(bf16x8, *(const ushort8*)&As[ar * 72 + kk * 32 + (l >> 4) * 8]);
      }
      #pragma unroll
      for (int ni = 0; ni < 4; ++ni){
        const int br = wn * 64 + ni * 16 + (l & 15);
        bv[ni] = __builtin_bit_cast(bf16x8, *(const ushort8*)&Bs[br * 72 + kk * 32 + (l >> 4) * 8]);
      }
      #pragma unroll
      for (int mi = 0; mi < 4; ++mi)
        #pragma unroll
        for (int ni = 0; ni < 4; ++ni)
          acc[mi][ni] = __builtin_amdgcn_mfma_f32_16x16x32_bf16(av[mi], bv[ni], acc[mi][ni], 0, 0, 0);
    }
    __syncthreads();
  }
  // quantize: Cs row-major [128][128]; Ct col-major [col][row] stride 144
  unsigned char* Cs = (unsigned char*)As;
  unsigned char* Ct = (unsigned char*)Bs;
  unsigned umf[4][4];   // [mi][rr]: max over ni (F-side chunk partial)
  unsigned umt[4];      // [ni]: max over mi,rr (T-side chunk partial)
  #pragma unroll
  for (int mi = 0; mi < 4; ++mi)
    #pragma unroll
    for (int rr = 0; rr < 4; ++rr) umf[mi][rr] = 0u;
  #pragma unroll
  for (int ni = 0; ni < 4; ++ni) umt[ni] = 0u;
  #pragma unroll
  for (int mi = 0; mi < 4; ++mi){
    const int rowb = wm * 64 + mi * 16 + (l >> 4) * 4;
    #pragma unroll
    for (int ni = 0; ni < 4; ++ni){
      const int col = wn * 64 + ni * 16 + (l & 15);
      unsigned pk = 0;
      #pragma unroll
      for (int rr = 0; rr < 4; ++rr){
        float q = fminf(fmaxf(acc[mi][ni][rr] * QS, -127.f), 127.f);
        unsigned b = (unsigned)((int)__builtin_rintf(q) + 128) & 255u;
        Cs[(rowb + rr) * 128 + col] = (unsigned char)b;
        pk |= b << (8 * rr);
        umf[mi][rr] = umax2(umf[mi][rr], b);
        umt[ni] = umax2(umt[ni], b);
      }
      *(unsigned*)(Ct + col * 144 + rowb) = pk;
    }
  }
  // F-side chunk max: reduce over 16 col-lanes (xor 1,2,4,8)
  #pragma unroll
  for (int mi = 0; mi < 4; ++mi)
    #pragma unroll
    for (int rr = 0; rr < 4; ++rr){
      unsigned v = umf[mi][rr];
      v = umax2(v, (unsigned)__shfl_xor((int)v, 1));
      v = umax2(v, (unsigned)__shfl_xor((int)v, 2));
      v = umax2(v, (unsigned)__shfl_xor((int)v, 4));
      v = umax2(v, (unsigned)__shfl_xor((int)v, 8));
      if ((l & 15) == 0)
        maxqF[(size_t)(brow + wm * 64 + mi * 16 + (l >> 4) * 4 + rr) * 128 + (bcol >> 6) + wn] = (unsigned char)v;
    }
  // T-side chunk max: reduce over the 4 row-subgroups (xor 16,32)
  #pragma unroll
  for (int ni = 0; ni < 4; ++ni){
    unsigned v = umt[ni];
    v = umax2(v, (unsigned)__shfl_xor((int)v, 16));
    v = umax2(v, (unsigned)__shfl_xor((int)v, 32));
    if ((l >> 4) == 0)
      maxqG[(size_t)(bcol + wn * 64 + ni * 16 + (l & 15)) * 128 + (brow >> 6) + wm] = (unsigned char)v;
  }
  __syncthreads();
  const int trow0 = t >> 3, kseg = t & 7;
  #pragma unroll
  for (int ii = 0; ii < 4; ++ii){
    const int row = trow0 + ii * 32;
    int4 v = *(const int4*)(Cs + row * 128 + kseg * 16);
    *(int4*)(zq + (size_t)(brow + row) * N + bcol + kseg * 16) = v;
    int4 vt = *(const int4*)(Ct + row * 144 + kseg * 16);
    *(int4*)(zqT + (size_t)(bcol + row) * N + brow + kseg * 16) = vt;
  }
}

// ---------------------------------------------------------------------------
// sweept: bootstrap dense sweep, full online-max tracking (1 row/wave).
// Stores pmax (lse) and seeds the next stage's gmax chunk-max chain.
// ---------------------------------------------------------------------------
__global__ __launch_bounds__(256) void sweept_k(const unsigned char* __restrict__ z,
                                                const float* __restrict__ din,
                                                float* __restrict__ dout,
                                                float* __restrict__ pmax_out,
                                                unsigned* __restrict__ gmax_out){
  const int w = threadIdx.x >> 6, l = threadIdx.x & 63;
  const int i = blockIdx.x * 4 + w;
  const unsigned char* zr = z + (size_t)i * N + l * 16;
  float m = -1e30f, s = 0.f;
  uint4 zA = *(const uint4*)(zr);
  #pragma unroll
  for (int it = 0; it < 8; ++it){
    uint4 zB = zA;
    if (it < 7) zB = *(const uint4*)(zr + (it + 1) * 1024);
    const float* gp = din + it * 1024 + l * 16;
    const float4 g0 = *(const float4*)(gp);
    const float4 g1 = *(const float4*)(gp + 4);
    const float4 g2 = *(const float4*)(gp + 8);
    const float4 g3 = *(const float4*)(gp + 12);
    float tt[16];
    tt[0]  = __builtin_fmaf(cub0(zA.x), ZS, g0.x);
    tt[1]  = __builtin_fmaf(cub1(zA.x), ZS, g0.y);
    tt[2]  = __builtin_fmaf(cub2(zA.x), ZS, g0.z);
    tt[3]  = __builtin_fmaf(cub3(zA.x), ZS, g0.w);
    tt[4]  = __builtin_fmaf(cub0(zA.y), ZS, g1.x);
    tt[5]  = __builtin_fmaf(cub1(zA.y), ZS, g1.y);
    tt[6]  = __builtin_fmaf(cub2(zA.y), ZS, g1.z);
    tt[7]  = __builtin_fmaf(cub3(zA.y), ZS, g1.w);
    tt[8]  = __builtin_fmaf(cub0(zA.z), ZS, g2.x);
    tt[9]  = __builtin_fmaf(cub1(zA.z), ZS, g2.y);
    tt[10] = __builtin_fmaf(cub2(zA.z), ZS, g2.z);
    tt[11] = __builtin_fmaf(cub3(zA.z), ZS, g2.w);
    tt[12] = __builtin_fmaf(cub0(zA.w), ZS, g3.x);
    tt[13] = __builtin_fmaf(cub1(zA.w), ZS, g3.y);
    tt[14] = __builtin_fmaf(cub2(zA.w), ZS, g3.z);
    tt[15] = __builtin_fmaf(cub3(zA.w), ZS, g3.w);
    float a0 = fmaxf(tt[0], tt[1]),  a1 = fmaxf(tt[2], tt[3]);
    float a2 = fmaxf(tt[4], tt[5]),  a3 = fmaxf(tt[6], tt[7]);
    float a4 = fmaxf(tt[8], tt[9]),  a5 = fmaxf(tt[10], tt[11]);
    float a6 = fmaxf(tt[12], tt[13]), a7 = fmaxf(tt[14], tt[15]);
    float b0 = fmaxf(a0, a1), b1 = fmaxf(a2, a3), b2 = fmaxf(a4, a5), b3 = fmaxf(a6, a7);
    float nm = fmaxf(fmaxf(fmaxf(b0, b1), fmaxf(b2, b3)), m);
    float s0 = ex2(tt[0] - nm) + ex2(tt[1] - nm) + ex2(tt[2] - nm) + ex2(tt[3] - nm)
             + ex2(tt[4] - nm) + ex2(tt[5] - nm) + ex2(tt[6] - nm) + ex2(tt[7] - nm);
    float s1 = ex2(tt[8] - nm) + ex2(tt[9] - nm) + ex2(tt[10] - nm) + ex2(tt[11] - nm)
             + ex2(tt[12] - nm) + ex2(tt[13] - nm) + ex2(tt[14] - nm) + ex2(tt[15] - nm);
    s = __builtin_fmaf(s, ex2(m - nm), s0 + s1);
    m = nm;
    zA = zB;
  }
  #pragma unroll
  for (int off = 32; off > 0; off >>= 1){
    float om = __shfl_down(m, off);
    float os = __shfl_down(s, off);
    float nm = fmaxf(m, om);
    s = __builtin_fmaf(s, ex2(m - nm), os * ex2(om - nm));
    m = nm;
  }
  if (l == 0){
    float lse2 = m + lg2(s);          // true lse2 (bias cancels)
    const float dv = 13.0f - lse2 - BIAS;
    dout[i] = dv;
    pmax_out[i] = lse2;
    atomicMax(gmax_out + (i >> 6), fkey(dv));
  }
}

// ---------------------------------------------------------------------------
// sweeps: chunk-skipping premax sweep over PHYSICAL 64-col chunks. 1 row/wave.
// Bound: maxq[r][c]*ZS + chunkmax(din)[c] > M - CUT  (both sides of bound
// include/cancel BIAS). Survivors ballot-compacted to LDS; processed 4
// chunks/iter: lane l does dword (l&15) of chunk list[k + (l>>4)].
// MODE 0: dout[r] = 13 - lse - BIAS ; pmax_out[r] = lse ; atomicMax gmax_out
// MODE 1: contrib[r] = (fprev_true*ln2 + x2)*2^(fprev_true + lse - 26)
// ---------------------------------------------------------------------------
template<int MODE>
__global__ __launch_bounds__(256) void sweeps_k(
    const unsigned char* __restrict__ z,
    const unsigned char* __restrict__ maxq,
    const float* __restrict__ din,
    const unsigned* __restrict__ gmax_in,
    float* __restrict__ dout,
    unsigned* __restrict__ gmax_out,
    const float* __restrict__ pmax_in,
    float* __restrict__ pmax_out,
    const float* __restrict__ fprev,
    const float* __restrict__ x2,
    float* __restrict__ contrib,
    float CUT){
  __shared__ unsigned short lists[4][128];
  const int w = threadIdx.x >> 6, l = threadIdx.x & 63;
  const int r = blockIdx.x * 4 + w;
  const float M = pmax_in[r];
  const unsigned char* mqp = maxq + (size_t)r * 128;
  const float thr = M - CUT;
  const float b0 = __builtin_fmaf((float)mqp[l],      ZS, fdec(gmax_in[l]));
  const float b1 = __builtin_fmaf((float)mqp[l + 64], ZS, fdec(gmax_in[l + 64]));
  const bool sv0 = b0 > thr, sv1 = b1 > thr;
  const unsigned long long m0 = __ballot(sv0), m1 = __ballot(sv1);
  const int S0 = __popcll(m0);
  int S = S0 + __popcll(m1);
  const unsigned long long low = (1ull << l) - 1ull;
  if (sv0) lists[w][__popcll(m0 & low)] = (unsigned short)l;
  if (sv1) lists[w][S0 + __popcll(m1 & low)] = (unsigned short)(l + 64);
  if (S == 0){ if (l == 0) lists[w][0] = 0; S = 1; }
  const unsigned* zr4 = (const unsigned*)(z + (size_t)r * N);
  const int sub = l >> 4, q16 = l & 15;
  float s = 0.f;
  #pragma unroll 2
  for (int k = 0; k < S; k += 4){
    int kk = k + sub;
    const bool act = kk < S;
    kk = act ? kk : S - 1;
    const int c = (int)lists[w][kk];
    const unsigned zd = zr4[c * 16 + q16];
    const float4 gv = *(const float4*)(din + (c << 6) + (q16 << 2));
    const float t0 = __builtin_fmaf(cub0(zd), ZS, gv.x - M);
    const float t1 = __builtin_fmaf(cub1(zd), ZS, gv.y - M);
    const float t2 = __builtin_fmaf(cub2(zd), ZS, gv.z - M);
    const float t3 = __builtin_fmaf(cub3(zd), ZS, gv.w - M);
    const float e = (ex2(t0) + ex2(t1)) + (ex2(t2) + ex2(t3));
    s += act ? e : 0.f;
  }
  #pragma unroll
  for (int off = 32; off > 0; off >>= 1) s += __shfl_down(s, off);
  if (l == 0){
    const float lse = M + lg2(s);
    if (MODE == 0){
      const float dv = 13.0f - lse - BIAS;
      dout[r] = dv;
      pmax_out[r] = lse;
      atomicMax(gmax_out + (r >> 6), fkey(dv));
    } else {
      const float fti = fprev[r] + BIAS;    // true FtL
      const float rr = ex2(fti + lse - 26.0f);
      contrib[r] = (fti * LN2 + x2[r]) * rr;
    }
  }
}

// ---------------------------------------------------------------------------
// finish: value = sum(contrib) + mean_j((gts_j+BIAS)*ln2 + y2_j); out = sqrt
// ---------------------------------------------------------------------------
__global__ __launch_bounds__(256) void finish_k(const float* __restrict__ contrib,
                                                const float* __restrict__ gts,
                                                const float* __restrict__ y2,
                                                float* __restrict__ out){
  __shared__ float s1[256], s2[256];
  const int t = threadIdx.x;
  float a = 0.f, b = 0.f;
  for (int j = t; j < N; j += 256){ a += contrib[j]; b += (gts[j] + BIAS) * LN2 + y2[j]; }
  s1[t] = a; s2[t] = b; __syncthreads();
  for (int st = 128; st > 0; st >>= 1){
    if (t < st){ s1[t] += s1[t + st]; s2[t] += s2[t + st]; }
    __syncthreads();
  }
  if (t == 0) out[0] = sqrtf(s1[0] + s2[0] * (1.0f / (float)N));
}

// ---------------------------------------------------------------------------
extern "C" void kernel_launch(void* const* d_in, const int* in_sizes, int n_in,
                              void* d_out, int out_size, void* d_ws, size_t ws_size,
                              hipStream_t stream){
  const float* x = (const float*)d_in[0];
  const float* y = (const float*)d_in[1];
  float* out = (float*)d_out;
  char* ws = (char*)d_ws;

  // workspace layout (bytes)
  unsigned char* zq    = (unsigned char*)(ws);              // 64 MiB
  unsigned char* zqT   = (unsigned char*)(ws + 67108864);   // 64 MiB
  u16*   xb     = (u16*)  (ws + 134217728);                 // 4 MiB
  u16*   yb     = (u16*)  (ws + 138412032);                 // 4 MiB
  unsigned char* maxqF = (unsigned char*)(ws + 142606336);  // 1 MiB
  unsigned char* maxqG = (unsigned char*)(ws + 143654912);  // 1 MiB
  char* fb = ws + 144703488;
  float* x2      = (float*)(fb);
  float* y2      = (float*)(fb + 32768);
  float* fts     = (float*)(fb + 65536);
  float* gts     = (float*)(fb + 98304);
  float* pmaxF   = (float*)(fb + 131072);
  float* pmaxG   = (float*)(fb + 163840);
  float* contrib = (float*)(fb + 196608);
  unsigned* gmax = (unsigned*)(fb + 229376);                // 102*128 uints

  zero_k<<<51, 256, 0, stream>>>(gmax);
  prep_k<<<4096, 256, 0, stream>>>(x, y, xb, yb, x2, y2, gts);
  gemm_k<<<dim3(64, 64), 256, 0, stream>>>(xb, yb, zq, zqT, maxqF, maxqG);
  // dense bootstrap: sweeps s=0..3 (f,g,f,g); each seeds gmax[s+1]
  sweept_k<<<2048, 256, 0, stream>>>(zq,  gts, fts, pmaxF, gmax + 1 * 128);
  sweept_k<<<2048, 256, 0, stream>>>(zqT, fts, gts, pmaxG, gmax + 2 * 128);
  sweept_k<<<2048, 256, 0, stream>>>(zq,  gts, fts, pmaxF, gmax + 3 * 128);
  sweept_k<<<2048, 256, 0, stream>>>(zqT, fts, gts, pmaxG, gmax + 4 * 128);
  // sparse sweeps: s=4..99 (even=f, odd=g); consume gmax[s], write gmax[s+1]
  for (int s = 4; s < 100; ++s){
    const float cut = (s < 6) ? 70.0f : 45.0f;
    if ((s & 1) == 0)
      sweeps_k<0><<<2048, 256, 0, stream>>>(zq,  maxqF, gts, gmax + s * 128,
                                            fts, gmax + (s + 1) * 128,
                                            pmaxF, pmaxF, nullptr, nullptr, nullptr, cut);
    else
      sweeps_k<0><<<2048, 256, 0, stream>>>(zqT, maxqG, fts, gmax + s * 128,
                                            gts, gmax + (s + 1) * 128,
                                            pmaxG, pmaxG, nullptr, nullptr, nullptr, cut);
  }
  // final value pass (f-side, sparse) + reduction
  sweeps_k<1><<<2048, 256, 0, stream>>>(zq, maxqF, gts, gmax + 100 * 128,
                                        nullptr, nullptr, pmaxF, nullptr,
                                        fts, x2, contrib, 45.0f);
  finish_k<<<1, 256, 0, stream>>>(contrib, gts, y2, out);
}

// Round 10
// 1708.277 us; speedup vs baseline: 2.5604x; 1.8108x over previous
//
#include <hip/hip_runtime.h>

#define N 8192
#define DK 256
#define LOG2E 1.4426950408889634f
#define LN2   0.6931471805599453f
#define ZS    2.5f            // int8 dequant scale (Zl = q * ZS)
#define QS    1.1541560327f   // 2*log2e / ZS  (fp32 acc -> q units)
#define BIAS  320.0f          // 128 * ZS ; duals stored shifted by -BIAS
// log2(8192) = 13 exactly; (loga+logb) in log2 units = -26

typedef unsigned short u16;
typedef u16   ushort8 __attribute__((ext_vector_type(8)));
typedef __bf16 bf16x8 __attribute__((ext_vector_type(8)));
typedef float  f32x4  __attribute__((ext_vector_type(4)));

__device__ __forceinline__ u16 f2bf(float f){
  unsigned u = __builtin_bit_cast(unsigned, f);
  return (u16)((u + 0x7fffu + ((u >> 16) & 1u)) >> 16);   // RNE fp32->bf16
}
__device__ __forceinline__ float ex2(float x){            // v_exp_f32 = 2^x
  float r; asm("v_exp_f32 %0, %1" : "=v"(r) : "v"(x)); return r;
}
__device__ __forceinline__ float lg2(float x){            // v_log_f32 = log2(x)
  float r; asm("v_log_f32 %0, %1" : "=v"(r) : "v"(x)); return r;
}
__device__ __forceinline__ float cub0(unsigned u){ float r; asm("v_cvt_f32_ubyte0 %0, %1":"=v"(r):"v"(u)); return r; }
__device__ __forceinline__ float cub1(unsigned u){ float r; asm("v_cvt_f32_ubyte1 %0, %1":"=v"(r):"v"(u)); return r; }
__device__ __forceinline__ float cub2(unsigned u){ float r; asm("v_cvt_f32_ubyte2 %0, %1":"=v"(r):"v"(u)); return r; }
__device__ __forceinline__ float cub3(unsigned u){ float r; asm("v_cvt_f32_ubyte3 %0, %1":"=v"(r):"v"(u)); return r; }

// sum of 4 exp2 terms for one row: t_e = q_e*ZS + (g_e - M)
__device__ __forceinline__ float quad(unsigned u, float4 gv, float M){
  float t0 = __builtin_fmaf(cub0(u), ZS, gv.x - M);
  float t1 = __builtin_fmaf(cub1(u), ZS, gv.y - M);
  float t2 = __builtin_fmaf(cub2(u), ZS, gv.z - M);
  float t3 = __builtin_fmaf(cub3(u), ZS, gv.w - M);
  return (ex2(t0) + ex2(t1)) + (ex2(t2) + ex2(t3));
}

// ---------------------------------------------------------------------------
// prep: row sum-of-squares + bf16 copies + init gts = -y2*LOG2E - BIAS (g0=0)
// ---------------------------------------------------------------------------
__global__ __launch_bounds__(256) void prep_k(const float* __restrict__ x, const float* __restrict__ y,
                                              u16* __restrict__ xb, u16* __restrict__ yb,
                                              float* __restrict__ x2, float* __restrict__ y2,
                                              float* __restrict__ gts){
  const int w = threadIdx.x >> 6, l = threadIdx.x & 63;
  const int r = blockIdx.x * 4 + w;         // 0..16383
  const bool isx = r < N;
  const int rr = isx ? r : r - N;
  const float* src = (isx ? x : y) + (size_t)rr * DK;
  float4 v = *(const float4*)(src + l * 4);
  ushort4 bv;
  bv.x = f2bf(v.x); bv.y = f2bf(v.y); bv.z = f2bf(v.z); bv.w = f2bf(v.w);
  *(ushort4*)((isx ? xb : yb) + (size_t)rr * DK + l * 4) = bv;
  float p = v.x*v.x + v.y*v.y + v.z*v.z + v.w*v.w;
  #pragma unroll
  for (int off = 32; off > 0; off >>= 1) p += __shfl_down(p, off);
  if (l == 0){
    if (isx) x2[rr] = p;
    else { y2[rr] = p; gts[rr] = -p * LOG2E - BIAS; }
  }
}

// ---------------------------------------------------------------------------
// gemm: z = xb*yb^T (bf16 MFMA). Quantize Zl = 2*log2e*z to biased uint8,
// stage tiles in LDS, store zq and zqT coalesced dwordx4.
// ---------------------------------------------------------------------------
__global__ __launch_bounds__(256) void gemm_k(const u16* __restrict__ xb, const u16* __restrict__ yb,
                                              unsigned char* __restrict__ zq,
                                              unsigned char* __restrict__ zqT){
  __shared__ __align__(16) u16 As[128 * 72];
  __shared__ __align__(16) u16 Bs[128 * 72];
  const int t = threadIdx.x;
  const int w = t >> 6, l = t & 63;
  const int wm = w >> 1, wn = w & 1;
  const int brow = blockIdx.y * 128, bcol = blockIdx.x * 128;
  const int tr = t >> 3, tc = t & 7;
  f32x4 acc[4][4] = {};
  for (int ks = 0; ks < 4; ++ks){
    #pragma unroll
    for (int rr = 0; rr < 4; ++rr){
      const int row = tr + rr * 32;
      *(ushort8*)&As[row * 72 + tc * 8] = *(const ushort8*)&xb[(size_t)(brow + row) * DK + ks * 64 + tc * 8];
      *(ushort8*)&Bs[row * 72 + tc * 8] = *(const ushort8*)&yb[(size_t)(bcol + row) * DK + ks * 64 + tc * 8];
    }
    __syncthreads();
    #pragma unroll
    for (int kk = 0; kk < 2; ++kk){
      bf16x8 av[4], bv[4];
      #pragma unroll
      for (int mi = 0; mi < 4; ++mi){
        const int ar = wm * 64 + mi * 16 + (l & 15);
        av[mi] = __builtin_bit_cast(bf16x8, *(const ushort8*)&As[ar * 72 + kk * 32 + (l >> 4) * 8]);
      }
      #pragma unroll
      for (int ni = 0; ni < 4; ++ni){
        const int br = wn * 64 + ni * 16 + (l & 15);
        bv[ni] = __builtin_bit_cast(bf16x8, *(const ushort8*)&Bs[br * 72 + kk * 32 + (l >> 4) * 8]);
      }
      #pragma unroll
      for (int mi = 0; mi < 4; ++mi)
        #pragma unroll
        for (int ni = 0; ni < 4; ++ni)
          acc[mi][ni] = __builtin_amdgcn_mfma_f32_16x16x32_bf16(av[mi], bv[ni], acc[mi][ni], 0, 0, 0);
    }
    __syncthreads();
  }
  // quantize: Cs row-major [128][128]; Ct col-major [col][row] stride 144
  unsigned char* Cs = (unsigned char*)As;
  unsigned char* Ct = (unsigned char*)Bs;
  #pragma unroll
  for (int mi = 0; mi < 4; ++mi){
    const int rowb = wm * 64 + mi * 16 + (l >> 4) * 4;
    #pragma unroll
    for (int ni = 0; ni < 4; ++ni){
      const int col = wn * 64 + ni * 16 + (l & 15);
      unsigned pk = 0;
      #pragma unroll
      for (int rr = 0; rr < 4; ++rr){
        float q = fminf(fmaxf(acc[mi][ni][rr] * QS, -127.f), 127.f);
        unsigned b = (unsigned)((int)__builtin_rintf(q) + 128) & 255u;
        Cs[(rowb + rr) * 128 + col] = (unsigned char)b;
        pk |= b << (8 * rr);
      }
      *(unsigned*)(Ct + col * 144 + rowb) = pk;
    }
  }
  __syncthreads();
  const int trow0 = t >> 3, kseg = t & 7;
  #pragma unroll
  for (int ii = 0; ii < 4; ++ii){
    const int row = trow0 + ii * 32;
    int4 v = *(const int4*)(Cs + row * 128 + kseg * 16);
    *(int4*)(zq + (size_t)(brow + row) * N + bcol + kseg * 16) = v;
    int4 vt = *(const int4*)(Ct + row * 144 + kseg * 16);
    *(int4*)(zqT + (size_t)(bcol + row) * N + brow + kseg * 16) = vt;
  }
}

// ---------------------------------------------------------------------------
// sweept: bootstrap dense sweep with full online-max tracking (1 row/wave).
// Also stores pmax_out[i] = lse2 for the premax kernels.
// ---------------------------------------------------------------------------
__global__ __launch_bounds__(256) void sweept_k(const unsigned char* __restrict__ z,
                                                const float* __restrict__ din,
                                                float* __restrict__ dout,
                                                float* __restrict__ pmax_out){
  const int w = threadIdx.x >> 6, l = threadIdx.x & 63;
  const int i = blockIdx.x * 4 + w;
  const unsigned char* zr = z + (size_t)i * N + l * 16;
  float m = -1e30f, s = 0.f;
  uint4 zA = *(const uint4*)(zr);
  #pragma unroll
  for (int it = 0; it < 8; ++it){
    uint4 zB = zA;
    if (it < 7) zB = *(const uint4*)(zr + (it + 1) * 1024);
    const float* gp = din + it * 1024 + l * 16;
    const float4 g0 = *(const float4*)(gp);
    const float4 g1 = *(const float4*)(gp + 4);
    const float4 g2 = *(const float4*)(gp + 8);
    const float4 g3 = *(const float4*)(gp + 12);
    float tt[16];
    tt[0]  = __builtin_fmaf(cub0(zA.x), ZS, g0.x);
    tt[1]  = __builtin_fmaf(cub1(zA.x), ZS, g0.y);
    tt[2]  = __builtin_fmaf(cub2(zA.x), ZS, g0.z);
    tt[3]  = __builtin_fmaf(cub3(zA.x), ZS, g0.w);
    tt[4]  = __builtin_fmaf(cub0(zA.y), ZS, g1.x);
    tt[5]  = __builtin_fmaf(cub1(zA.y), ZS, g1.y);
    tt[6]  = __builtin_fmaf(cub2(zA.y), ZS, g1.z);
    tt[7]  = __builtin_fmaf(cub3(zA.y), ZS, g1.w);
    tt[8]  = __builtin_fmaf(cub0(zA.z), ZS, g2.x);
    tt[9]  = __builtin_fmaf(cub1(zA.z), ZS, g2.y);
    tt[10] = __builtin_fmaf(cub2(zA.z), ZS, g2.z);
    tt[11] = __builtin_fmaf(cub3(zA.z), ZS, g2.w);
    tt[12] = __builtin_fmaf(cub0(zA.w), ZS, g3.x);
    tt[13] = __builtin_fmaf(cub1(zA.w), ZS, g3.y);
    tt[14] = __builtin_fmaf(cub2(zA.w), ZS, g3.z);
    tt[15] = __builtin_fmaf(cub3(zA.w), ZS, g3.w);
    float a0 = fmaxf(tt[0], tt[1]),  a1 = fmaxf(tt[2], tt[3]);
    float a2 = fmaxf(tt[4], tt[5]),  a3 = fmaxf(tt[6], tt[7]);
    float a4 = fmaxf(tt[8], tt[9]),  a5 = fmaxf(tt[10], tt[11]);
    float a6 = fmaxf(tt[12], tt[13]), a7 = fmaxf(tt[14], tt[15]);
    float b0 = fmaxf(a0, a1), b1 = fmaxf(a2, a3), b2 = fmaxf(a4, a5), b3 = fmaxf(a6, a7);
    float nm = fmaxf(fmaxf(fmaxf(b0, b1), fmaxf(b2, b3)), m);
    float s0 = ex2(tt[0] - nm) + ex2(tt[1] - nm) + ex2(tt[2] - nm) + ex2(tt[3] - nm)
             + ex2(tt[4] - nm) + ex2(tt[5] - nm) + ex2(tt[6] - nm) + ex2(tt[7] - nm);
    float s1 = ex2(tt[8] - nm) + ex2(tt[9] - nm) + ex2(tt[10] - nm) + ex2(tt[11] - nm)
             + ex2(tt[12] - nm) + ex2(tt[13] - nm) + ex2(tt[14] - nm) + ex2(tt[15] - nm);
    s = __builtin_fmaf(s, ex2(m - nm), s0 + s1);
    m = nm;
    zA = zB;
  }
  #pragma unroll
  for (int off = 32; off > 0; off >>= 1){
    float om = __shfl_down(m, off);
    float os = __shfl_down(s, off);
    float nm = fmaxf(m, om);
    s = __builtin_fmaf(s, ex2(m - nm), os * ex2(om - nm));
    m = nm;
  }
  if (l == 0){
    float lse2 = m + lg2(s);          // true lse2 (bias cancels)
    dout[i] = 13.0f - lse2 - BIAS;
    pmax_out[i] = lse2;
  }
}

// ---------------------------------------------------------------------------
// sweepn: premax dense sweep with LDS-resident duals.
// Block = 256 threads = 4 waves; each wave owns 2 rows; block covers 8 rows
// (grid 1024). The full 32KB dual array is staged to LDS once per block, so
// per-element dual reads never touch L1/L2 (which z streaming thrashes).
// Each ds_read_b128 of duals is shared by the wave's 2 rows.
// s = sum 2^(t - M), M = this row's previous-sweep lse (premax, exact math).
// MODE 0: dout[r] = 13 - lse - BIAS ; pmax_out[r] = lse
// MODE 1: r = 2^(fprev_true + lse - 26); contrib = (fprev_true*ln2 + x2)*r
// ---------------------------------------------------------------------------
template<int MODE>
__global__ __launch_bounds__(256) void sweepn_k(const unsigned char* __restrict__ z,
                                                const float* __restrict__ din,
                                                float* __restrict__ dout,
                                                const float* __restrict__ pmax_in,
                                                float* __restrict__ pmax_out,
                                                const float* __restrict__ fprev,
                                                const float* __restrict__ x2,
                                                float* __restrict__ contrib){
  __shared__ __align__(16) float gl[8192];
  const int t = threadIdx.x;
  #pragma unroll
  for (int i = 0; i < 8; ++i){
    const int idx = (t + i * 256) * 4;
    *(float4*)(gl + idx) = *(const float4*)(din + idx);
  }
  __syncthreads();
  const int w = t >> 6, l = t & 63;
  const int r0 = blockIdx.x * 8 + w * 2;
  const unsigned char* zr = z + (size_t)r0 * N + l * 16;
  const float M0 = pmax_in[r0], M1 = pmax_in[r0 + 1];
  float s0 = 0.f, s1 = 0.f;
  #pragma unroll 2
  for (int it = 0; it < 8; ++it){
    const uint4 a = *(const uint4*)(zr + it * 1024);
    const uint4 b = *(const uint4*)(zr + N + it * 1024);
    const int cb = it * 1024 + l * 16;
    {
      const float4 gv = *(const float4*)(gl + cb);
      s0 += quad(a.x, gv, M0); s1 += quad(b.x, gv, M1);
    }
    {
      const float4 gv = *(const float4*)(gl + cb + 4);
      s0 += quad(a.y, gv, M0); s1 += quad(b.y, gv, M1);
    }
    {
      const float4 gv = *(const float4*)(gl + cb + 8);
      s0 += quad(a.z, gv, M0); s1 += quad(b.z, gv, M1);
    }
    {
      const float4 gv = *(const float4*)(gl + cb + 12);
      s0 += quad(a.w, gv, M0); s1 += quad(b.w, gv, M1);
    }
  }
  #pragma unroll
  for (int off = 32; off > 0; off >>= 1){
    s0 += __shfl_down(s0, off);
    s1 += __shfl_down(s1, off);
  }
  if (l == 0){
    const float lse0 = M0 + lg2(s0);
    const float lse1 = M1 + lg2(s1);
    if (MODE == 0){
      dout[r0]     = 13.0f - lse0 - BIAS;
      dout[r0 + 1] = 13.0f - lse1 - BIAS;
      pmax_out[r0]     = lse0;
      pmax_out[r0 + 1] = lse1;
    } else {
      const float f0 = fprev[r0] + BIAS;        // true FtL
      const float f1 = fprev[r0 + 1] + BIAS;
      contrib[r0]     = (f0 * LN2 + x2[r0])     * ex2(f0 + lse0 - 26.0f);
      contrib[r0 + 1] = (f1 * LN2 + x2[r0 + 1]) * ex2(f1 + lse1 - 26.0f);
    }
  }
}

// ---------------------------------------------------------------------------
// finish: value = sum(contrib) + mean_j((gts_j+BIAS)*ln2 + y2_j); out = sqrt
// ---------------------------------------------------------------------------
__global__ __launch_bounds__(256) void finish_k(const float* __restrict__ contrib,
                                                const float* __restrict__ gts,
                                                const float* __restrict__ y2,
                                                float* __restrict__ out){
  __shared__ float s1[256], s2[256];
  const int t = threadIdx.x;
  float a = 0.f, b = 0.f;
  for (int j = t; j < N; j += 256){ a += contrib[j]; b += (gts[j] + BIAS) * LN2 + y2[j]; }
  s1[t] = a; s2[t] = b; __syncthreads();
  for (int st = 128; st > 0; st >>= 1){
    if (t < st){ s1[t] += s1[t + st]; s2[t] += s2[t + st]; }
    __syncthreads();
  }
  if (t == 0) out[0] = sqrtf(s1[0] + s2[0] * (1.0f / (float)N));
}

// ---------------------------------------------------------------------------
extern "C" void kernel_launch(void* const* d_in, const int* in_sizes, int n_in,
                              void* d_out, int out_size, void* d_ws, size_t ws_size,
                              hipStream_t stream){
  const float* x = (const float*)d_in[0];
  const float* y = (const float*)d_in[1];
  float* out = (float*)d_out;
  char* ws = (char*)d_ws;

  // workspace layout (bytes)
  unsigned char* zq  = (unsigned char*)(ws);              // 64 MiB
  unsigned char* zqT = (unsigned char*)(ws + 67108864);   // 64 MiB
  u16*   xb      = (u16*)  (ws + 134217728);              // 4 MiB
  u16*   yb      = (u16*)  (ws + 138412032);              // 4 MiB
  float* x2      = (float*)(ws + 142606336);
  float* y2      = (float*)(ws + 142639104);
  float* fts     = (float*)(ws + 142671872);
  float* gts     = (float*)(ws + 142704640);
  float* contrib = (float*)(ws + 142737408);
  float* pmaxF   = (float*)(ws + 142770176);
  float* pmaxG   = (float*)(ws + 142802944);

  prep_k<<<4096, 256, 0, stream>>>(x, y, xb, yb, x2, y2, gts);
  gemm_k<<<dim3(64, 64), 256, 0, stream>>>(xb, yb, zq, zqT);
  // bootstrap: 2 full iterations with online max (seeds pmax + duals)
  for (int it = 0; it < 2; ++it){
    sweept_k<<<2048, 256, 0, stream>>>(zq,  gts, fts, pmaxF);
    sweept_k<<<2048, 256, 0, stream>>>(zqT, fts, gts, pmaxG);
  }
  // premax sweeps with LDS-resident duals: s = 4..99 (even=f, odd=g)
  for (int s = 4; s < 100; ++s){
    if ((s & 1) == 0)
      sweepn_k<0><<<1024, 256, 0, stream>>>(zq,  gts, fts, pmaxF, pmaxF,
                                            nullptr, nullptr, nullptr);
    else
      sweepn_k<0><<<1024, 256, 0, stream>>>(zqT, fts, gts, pmaxG, pmaxG,
                                            nullptr, nullptr, nullptr);
  }
  // final value pass (f-side) + reduction
  sweepn_k<1><<<1024, 256, 0, stream>>>(zq, gts, nullptr, pmaxF, nullptr,
                                        fts, x2, contrib);
  finish_k<<<1, 256, 0, stream>>>(contrib, gts, y2, out);
}